// Round 2
// baseline (268.335 us; speedup 1.0000x reference)
//
#include <hip/hip_runtime.h>
#include <hip/hip_bf16.h>

#define S_ 4
#define B_ 256
#define L_ 256
#define D_ 512
#define NQ_ 4
#define H_ 2048
#define G_ 3072

typedef __attribute__((ext_vector_type(4))) float f32x4;
typedef __attribute__((ext_vector_type(8))) short s16x8;

__device__ __forceinline__ unsigned short f2bf(float x) {
    __hip_bfloat16 hb = __float2bfloat16(x);
    return reinterpret_cast<unsigned short&>(hb);
}

// block-wide sum for 256-thread blocks; red is __shared__ float[8]
__device__ __forceinline__ float block_sum256(float v, float* red) {
    #pragma unroll
    for (int off = 32; off > 0; off >>= 1) v += __shfl_down(v, off, 64);
    int tid = threadIdx.x;
    int lane = tid & 63, wid = tid >> 6;
    if (lane == 0) red[wid] = v;
    __syncthreads();
    float r = (tid < 4) ? red[tid] : 0.f;
    #pragma unroll
    for (int off = 4; off > 0; off >>= 1) r += __shfl_down(r, off, 64);
    if (tid == 0) red[0] = r;
    __syncthreads();
    float out = red[0];
    __syncthreads();
    return out;
}

// ---------------- kernel 1: masked mean pool over L ----------------
// grid: S_*B_ blocks, 256 threads. Reads 537 MB -> memory-bound streamer.
// Mask dtype is auto-detected: harness passes numpy bool either as int32
// ("integer -> const int*") or as raw 1-byte bool. If 1-byte, the 768
// non-word-aligned bytes of the first 1 KiB are random 0/1 -> P(all zero)
// ~ 2^-768. So "all non-aligned bytes zero" => int32. Deterministic.
__global__ __launch_bounds__(256) void pool_kernel(
    const float* __restrict__ seq_tokens,
    const unsigned char* __restrict__ masks_raw,
    float* __restrict__ pooled)                // (S,B,D)
{
    const int sb = blockIdx.x;
    const int tid = threadIdx.x;
    __shared__ float sval[L_];
    __shared__ float scount[4];
    __shared__ f32x4 spart[256];
    __shared__ int is_bool_flag;

    if (tid == 0) is_bool_flag = 0;
    __syncthreads();
    // probe first 256 words (1 KiB): any nonzero byte at offset%4!=0 => bool
    {
        unsigned int w = reinterpret_cast<const unsigned int*>(masks_raw)[tid];
        if (w & 0xFFFFFF00u) is_bool_flag = 1;   // benign race, same value
    }
    __syncthreads();
    const bool is_bool = (is_bool_flag != 0);

    int mval;
    if (is_bool) {
        mval = masks_raw[(size_t)sb * L_ + tid];
    } else {
        mval = reinterpret_cast<const int*>(masks_raw)[(size_t)sb * L_ + tid];
    }
    float valid = mval ? 0.f : 1.f;
    sval[tid] = valid;
    float c = valid;
    #pragma unroll
    for (int off = 32; off > 0; off >>= 1) c += __shfl_down(c, off, 64);
    if ((tid & 63) == 0) scount[tid >> 6] = c;
    __syncthreads();
    const float denom = fmaxf(scount[0] + scount[1] + scount[2] + scount[3], 1.f);

    const float* base = seq_tokens + (size_t)sb * L_ * D_;
    const int cidx = tid & 127;   // float4 column
    const int rg = tid >> 7;      // 0/1
    f32x4 acc = {0.f, 0.f, 0.f, 0.f};
    for (int l = rg; l < L_; l += 2) {
        float vl = sval[l];
        f32x4 v = *reinterpret_cast<const f32x4*>(base + (size_t)l * D_ + cidx * 4);
        acc += v * vl;
    }
    spart[tid] = acc;
    __syncthreads();
    if (tid < 128) {
        f32x4 r = spart[tid] + spart[tid + 128];
        r *= (1.f / denom);
        *reinterpret_cast<f32x4*>(pooled + (size_t)sb * D_ + cidx * 4) = r;
    }
}

// ---------------- kernel 2: stat proj + LN, concat, group-input LN -> gi (bf16) ----------------
// grid: S_*B_ blocks, 256 threads
__global__ __launch_bounds__(256) void gi_kernel(
    const float* __restrict__ ns_tokens,    // (B, 2048)
    const float* __restrict__ seq_stats,    // (S,B,6)
    const float* __restrict__ stat_W,       // (S,6,D)
    const float* __restrict__ stat_b,       // (S,D)
    const float* __restrict__ stat_ln_g,
    const float* __restrict__ stat_ln_b,
    const float* __restrict__ gin_gamma,    // (G)
    const float* __restrict__ gin_beta,
    const float* __restrict__ pooled,       // (S,B,D)
    __hip_bfloat16* __restrict__ gi)        // (S,B,G)
{
    const int sb = blockIdx.x;
    const int s = sb >> 8;
    const int b = sb & 255;
    const int tid = threadIdx.x;
    __shared__ float red[8];
    __shared__ float sstat[D_];

    float st[6];
    #pragma unroll
    for (int f = 0; f < 6; ++f) st[f] = seq_stats[(size_t)sb * 6 + f];

    float sp[2];
    #pragma unroll
    for (int k = 0; k < 2; ++k) {
        int d = tid + k * 256;
        float a = stat_b[s * D_ + d];
        #pragma unroll
        for (int f = 0; f < 6; ++f) a += st[f] * stat_W[(s * 6 + f) * D_ + d];
        sp[k] = a;
    }
    float ssum = block_sum256(sp[0] + sp[1], red);
    float ssq  = block_sum256(sp[0] * sp[0] + sp[1] * sp[1], red);
    float mu = ssum / D_;
    float var = ssq / D_ - mu * mu;
    float rinv = rsqrtf(var + 1e-5f);
    #pragma unroll
    for (int k = 0; k < 2; ++k) {
        int d = tid + k * 256;
        sstat[d] = (sp[k] - mu) * rinv * stat_ln_g[s * D_ + d] + stat_ln_b[s * D_ + d];
    }
    __syncthreads();

    float gv[12];
    float gsum = 0.f, gsq = 0.f;
    #pragma unroll
    for (int k = 0; k < 12; ++k) {
        int g = tid + k * 256;
        float v;
        if (g < 2048)       v = ns_tokens[(size_t)b * 2048 + g];
        else if (g < 2560)  v = pooled[(size_t)sb * D_ + (g - 2048)];
        else                v = sstat[g - 2560];
        gv[k] = v;
        gsum += v;
        gsq += v * v;
    }
    gsum = block_sum256(gsum, red);
    gsq  = block_sum256(gsq, red);
    mu = gsum / G_;
    var = gsq / G_ - mu * mu;
    rinv = rsqrtf(var + 1e-5f);
    #pragma unroll
    for (int k = 0; k < 12; ++k) {
        int g = tid + k * 256;
        float o = (gv[k] - mu) * rinv * gin_gamma[g] + gin_beta[g];
        gi[(size_t)sb * G_ + g] = __float2bfloat16(o);
    }
}

// ---------------- kernel 3: GEMM1  h = silu(gi @ W1 + b1)  ----------------
// per (s,q): (256 x 3072) x (3072 x 2048). BM=256 (W1 read exactly once), BN=64, BK=64.
// 4 waves, each 64x64 output (4x4 fragments of 16x16x32 bf16 MFMA).
// W1 is N-contiguous -> staged with in-register 4x4 transpose into K-contiguous LDS.
// XOR swizzle on 16B chunks: swz = (row ^ (row>>3)) & 7  (spreads both read and write patterns).
__global__ __launch_bounds__(256) void gemm1_kernel(
    const __hip_bfloat16* __restrict__ gi,
    const float* __restrict__ W1,
    const float* __restrict__ b1,
    __hip_bfloat16* __restrict__ hbuf)      // (S*Nq, B, H)
{
    const int ntile = blockIdx.x;   // 0..31
    const int sq = blockIdx.y;      // 0..15
    const int s = sq >> 2;
    const int tid = threadIdx.x;
    const int lane = tid & 63;
    const int wid = tid >> 6;       // 0..3 (wave m-block)

    __shared__ __align__(16) unsigned short As[256 * 64];
    __shared__ __align__(16) unsigned short Ws[64 * 64];

    const __hip_bfloat16* Ab = gi + (size_t)s * B_ * G_;
    const float* Wb = W1 + (size_t)sq * G_ * H_ + ntile * 64;

    f32x4 acc[4][4];
    #pragma unroll
    for (int i = 0; i < 4; ++i)
        #pragma unroll
        for (int j = 0; j < 4; ++j) acc[i][j] = (f32x4){0.f, 0.f, 0.f, 0.f};

    const int wn0 = (tid & 15) * 4;   // W stage: n block
    const int wk0 = (tid >> 4) * 4;   // W stage: k block

    for (int kt = 0; kt < G_ / 64; ++kt) {
        const int kbase = kt * 64;
        __syncthreads();
        // A stage: 256x64 bf16, swizzled
        #pragma unroll
        for (int i = 0; i < 8; ++i) {
            int slot = i * 256 + tid;
            int row = slot >> 3, cc = slot & 7;
            int swz = (row ^ (row >> 3)) & 7;
            s16x8 v = *reinterpret_cast<const s16x8*>(Ab + (size_t)row * G_ + kbase + cc * 8);
            *reinterpret_cast<s16x8*>(&As[row * 64 + ((cc ^ swz) * 8)]) = v;
        }
        // W stage: 64k x 64n f32 -> Ws[n][k] bf16 (transpose in registers)
        float wv[4][4];
        #pragma unroll
        for (int kk = 0; kk < 4; ++kk) {
            f32x4 t = *reinterpret_cast<const f32x4*>(Wb + (size_t)(kbase + wk0 + kk) * H_ + wn0);
            #pragma unroll
            for (int j = 0; j < 4; ++j) wv[kk][j] = t[j];
        }
        #pragma unroll
        for (int nn = 0; nn < 4; ++nn) {
            int row = wn0 + nn;
            int swz = (row ^ (row >> 3)) & 7;
            unsigned long long pk =
                (unsigned long long)f2bf(wv[0][nn]) |
                ((unsigned long long)f2bf(wv[1][nn]) << 16) |
                ((unsigned long long)f2bf(wv[2][nn]) << 32) |
                ((unsigned long long)f2bf(wv[3][nn]) << 48);
            int byteoff = (row * 128 + wk0 * 2) ^ (swz << 4);
            *reinterpret_cast<unsigned long long*>(reinterpret_cast<char*>(Ws) + byteoff) = pk;
        }
        __syncthreads();
        #pragma unroll
        for (int kb = 0; kb < 2; ++kb) {
            s16x8 af[4], bfr[4];
            #pragma unroll
            for (int mi = 0; mi < 4; ++mi) {
                int r = wid * 64 + mi * 16 + (lane & 15);
                int swz = (r ^ (r >> 3)) & 7;
                int chunk = ((lane >> 4) + kb * 4) ^ swz;
                af[mi] = *reinterpret_cast<const s16x8*>(&As[r * 64 + chunk * 8]);
            }
            #pragma unroll
            for (int ni = 0; ni < 4; ++ni) {
                int r = ni * 16 + (lane & 15);
                int swz = (r ^ (r >> 3)) & 7;
                int chunk = ((lane >> 4) + kb * 4) ^ swz;
                bfr[ni] = *reinterpret_cast<const s16x8*>(&Ws[r * 64 + chunk * 8]);
            }
            #pragma unroll
            for (int mi = 0; mi < 4; ++mi)
                #pragma unroll
                for (int ni = 0; ni < 4; ++ni)
                    acc[mi][ni] = __builtin_amdgcn_mfma_f32_16x16x32_bf16(af[mi], bfr[ni], acc[mi][ni], 0, 0, 0);
        }
    }
    // epilogue: + b1, silu, bf16 store
    const float* b1p = b1 + (size_t)sq * H_ + ntile * 64;
    __hip_bfloat16* hp = hbuf + (size_t)sq * B_ * H_;
    #pragma unroll
    for (int mi = 0; mi < 4; ++mi)
        #pragma unroll
        for (int ni = 0; ni < 4; ++ni)
            #pragma unroll
            for (int r = 0; r < 4; ++r) {
                int row = wid * 64 + mi * 16 + ((lane >> 4) << 2) + r;
                int coll = ni * 16 + (lane & 15);
                float x = acc[mi][ni][r] + b1p[coll];
                float sg = 1.f / (1.f + __expf(-x));
                hp[(size_t)row * H_ + ntile * 64 + coll] = __float2bfloat16(x * sg);
            }
}

// ---------------- kernel 4: GEMM2  qpre = h @ W2 ----------------
// per (s,q): (256 x 2048) x (2048 x 512). BM=128, BN=64, BK=64, 4 waves (2x2), wave = 64x32.
__global__ __launch_bounds__(256) void gemm2_kernel(
    const __hip_bfloat16* __restrict__ hbuf,
    const float* __restrict__ W2,
    float* __restrict__ qpre)               // (S*Nq, B, D)
{
    const int ntile = blockIdx.x;   // 0..7
    const int mtile = blockIdx.y;   // 0..1
    const int sq = blockIdx.z;      // 0..15
    const int tid = threadIdx.x;
    const int lane = tid & 63;
    const int wid = tid >> 6;
    const int wm = wid >> 1, wn = wid & 1;

    __shared__ __align__(16) unsigned short As[128 * 64];
    __shared__ __align__(16) unsigned short Ws[64 * 64];

    const __hip_bfloat16* Ab = hbuf + ((size_t)sq * B_ + mtile * 128) * H_;
    const float* Wb = W2 + (size_t)sq * H_ * D_ + ntile * 64;

    f32x4 acc[4][2];
    #pragma unroll
    for (int i = 0; i < 4; ++i)
        #pragma unroll
        for (int j = 0; j < 2; ++j) acc[i][j] = (f32x4){0.f, 0.f, 0.f, 0.f};

    const int wn0 = (tid & 15) * 4;
    const int wk0 = (tid >> 4) * 4;

    for (int kt = 0; kt < H_ / 64; ++kt) {
        const int kbase = kt * 64;
        __syncthreads();
        #pragma unroll
        for (int i = 0; i < 4; ++i) {
            int slot = i * 256 + tid;
            int row = slot >> 3, cc = slot & 7;
            int swz = (row ^ (row >> 3)) & 7;
            s16x8 v = *reinterpret_cast<const s16x8*>(Ab + (size_t)row * H_ + kbase + cc * 8);
            *reinterpret_cast<s16x8*>(&As[row * 64 + ((cc ^ swz) * 8)]) = v;
        }
        float wv[4][4];
        #pragma unroll
        for (int kk = 0; kk < 4; ++kk) {
            f32x4 t = *reinterpret_cast<const f32x4*>(Wb + (size_t)(kbase + wk0 + kk) * D_ + wn0);
            #pragma unroll
            for (int j = 0; j < 4; ++j) wv[kk][j] = t[j];
        }
        #pragma unroll
        for (int nn = 0; nn < 4; ++nn) {
            int row = wn0 + nn;
            int swz = (row ^ (row >> 3)) & 7;
            unsigned long long pk =
                (unsigned long long)f2bf(wv[0][nn]) |
                ((unsigned long long)f2bf(wv[1][nn]) << 16) |
                ((unsigned long long)f2bf(wv[2][nn]) << 32) |
                ((unsigned long long)f2bf(wv[3][nn]) << 48);
            int byteoff = (row * 128 + wk0 * 2) ^ (swz << 4);
            *reinterpret_cast<unsigned long long*>(reinterpret_cast<char*>(Ws) + byteoff) = pk;
        }
        __syncthreads();
        #pragma unroll
        for (int kb = 0; kb < 2; ++kb) {
            s16x8 af[4], bfr[2];
            #pragma unroll
            for (int mi = 0; mi < 4; ++mi) {
                int r = wm * 64 + mi * 16 + (lane & 15);
                int swz = (r ^ (r >> 3)) & 7;
                int chunk = ((lane >> 4) + kb * 4) ^ swz;
                af[mi] = *reinterpret_cast<const s16x8*>(&As[r * 64 + chunk * 8]);
            }
            #pragma unroll
            for (int ni = 0; ni < 2; ++ni) {
                int r = wn * 32 + ni * 16 + (lane & 15);
                int swz = (r ^ (r >> 3)) & 7;
                int chunk = ((lane >> 4) + kb * 4) ^ swz;
                bfr[ni] = *reinterpret_cast<const s16x8*>(&Ws[r * 64 + chunk * 8]);
            }
            #pragma unroll
            for (int mi = 0; mi < 4; ++mi)
                #pragma unroll
                for (int ni = 0; ni < 2; ++ni)
                    acc[mi][ni] = __builtin_amdgcn_mfma_f32_16x16x32_bf16(af[mi], bfr[ni], acc[mi][ni], 0, 0, 0);
        }
    }
    #pragma unroll
    for (int mi = 0; mi < 4; ++mi)
        #pragma unroll
        for (int ni = 0; ni < 2; ++ni)
            #pragma unroll
            for (int r = 0; r < 4; ++r) {
                int row = mtile * 128 + wm * 64 + mi * 16 + ((lane >> 4) << 2) + r;
                int col = ntile * 64 + wn * 32 + ni * 16 + (lane & 15);
                qpre[((size_t)sq * B_ + row) * D_ + col] = acc[mi][ni][r];
            }
}

// ---------------- kernel 5: +b2, LayerNorm over D, transposed write ----------------
// grid: S*Nq*B blocks (4096), 256 threads
__global__ __launch_bounds__(256) void lnout_kernel(
    const float* __restrict__ qpre,   // (S*Nq, B, D)
    const float* __restrict__ b2,     // (S,Nq,D)
    const float* __restrict__ lng,    // (S,Nq,D)
    const float* __restrict__ lnb,
    float* __restrict__ out)          // (S,B,Nq,D)
{
    const int idx = blockIdx.x;       // sq*B + b
    const int sq = idx >> 8;
    const int b = idx & 255;
    const int tid = threadIdx.x;
    __shared__ float red[8];

    float v[2];
    #pragma unroll
    for (int k = 0; k < 2; ++k) {
        int d = tid + k * 256;
        v[k] = qpre[(size_t)idx * D_ + d] + b2[sq * D_ + d];
    }
    float sum = block_sum256(v[0] + v[1], red);
    float sq2 = block_sum256(v[0] * v[0] + v[1] * v[1], red);
    float mu = sum / D_;
    float var = sq2 / D_ - mu * mu;
    float rinv = rsqrtf(var + 1e-5f);
    const int s = sq >> 2, q = sq & 3;
    #pragma unroll
    for (int k = 0; k < 2; ++k) {
        int d = tid + k * 256;
        float o = (v[k] - mu) * rinv * lng[sq * D_ + d] + lnb[sq * D_ + d];
        out[(((size_t)s * B_ + b) * NQ_ + q) * D_ + d] = o;
    }
}

extern "C" void kernel_launch(void* const* d_in, const int* in_sizes, int n_in,
                              void* d_out, int out_size, void* d_ws, size_t ws_size,
                              hipStream_t stream) {
    const float* ns_tokens   = (const float*)d_in[0];
    const float* seq_tokens  = (const float*)d_in[1];
    const unsigned char* masks = (const unsigned char*)d_in[2];
    const float* seq_stats   = (const float*)d_in[3];
    const float* gin_gamma   = (const float*)d_in[4];
    const float* gin_beta    = (const float*)d_in[5];
    const float* stat_W      = (const float*)d_in[6];
    const float* stat_b      = (const float*)d_in[7];
    const float* stat_ln_g   = (const float*)d_in[8];
    const float* stat_ln_b   = (const float*)d_in[9];
    const float* W1          = (const float*)d_in[10];
    const float* b1          = (const float*)d_in[11];
    const float* W2          = (const float*)d_in[12];
    const float* b2          = (const float*)d_in[13];
    const float* ln_g        = (const float*)d_in[14];
    const float* ln_b        = (const float*)d_in[15];
    float* out = (float*)d_out;

    // workspace layout (bytes): pooled f32 2 MB | gi bf16 6 MB | h bf16 16 MB | qpre f32 8 MB
    char* ws = (char*)d_ws;
    float* pooled        = (float*)(ws);
    __hip_bfloat16* gi   = (__hip_bfloat16*)(ws + 2097152);
    __hip_bfloat16* hbuf = (__hip_bfloat16*)(ws + 2097152 + 6291456);
    float* qpre          = (float*)(ws + 2097152 + 6291456 + 16777216);

    pool_kernel<<<dim3(S_ * B_), dim3(256), 0, stream>>>(seq_tokens, masks, pooled);
    gi_kernel<<<dim3(S_ * B_), dim3(256), 0, stream>>>(ns_tokens, seq_stats, stat_W, stat_b,
                                                       stat_ln_g, stat_ln_b, gin_gamma, gin_beta,
                                                       pooled, gi);
    gemm1_kernel<<<dim3(H_ / 64, S_ * NQ_), dim3(256), 0, stream>>>(gi, W1, b1, hbuf);
    gemm2_kernel<<<dim3(D_ / 64, B_ / 128, S_ * NQ_), dim3(256), 0, stream>>>(hbuf, W2, qpre);
    lnout_kernel<<<dim3(S_ * NQ_ * B_), dim3(256), 0, stream>>>(qpre, b2, ln_g, ln_b, out);
}